// Round 2
// baseline (565.634 us; speedup 1.0000x reference)
//
#include <hip/hip_runtime.h>
#include <hip/hip_bf16.h>

typedef unsigned long long u64;

// ---------------- CSR build ----------------

__global__ void count_kernel(const int* __restrict__ dst, int* __restrict__ cnt, int E) {
    int e = blockIdx.x * blockDim.x + threadIdx.x;
    if (e < E) atomicAdd(&cnt[dst[e]], 1);
}

__global__ void norm_kernel(const int* __restrict__ cnt, float* __restrict__ nrm, int N) {
    int n = blockIdx.x * blockDim.x + threadIdx.x;
    if (n < N) nrm[n] = rsqrtf((float)cnt[n] + 1.0f);
}

// single-workgroup chunked Hillis-Steele exclusive scan (N=50000 -> 49 chunks)
__global__ void scan_kernel(const int* __restrict__ cnt, int* __restrict__ off, int n) {
    __shared__ int buf[1024];
    __shared__ int carry;
    if (threadIdx.x == 0) carry = 0;
    __syncthreads();
    for (int base = 0; base < n; base += 1024) {
        int i = base + threadIdx.x;
        int v = (i < n) ? cnt[i] : 0;
        buf[threadIdx.x] = v;
        __syncthreads();
        #pragma unroll
        for (int s = 1; s < 1024; s <<= 1) {
            int t = (threadIdx.x >= s) ? buf[threadIdx.x - s] : 0;
            __syncthreads();
            buf[threadIdx.x] += t;
            __syncthreads();
        }
        int incl = buf[threadIdx.x];
        if (i < n) off[i] = carry + incl - v;   // exclusive
        __syncthreads();                         // everyone read carry before update
        if (threadIdx.x == 1023) carry += buf[1023];
        __syncthreads();
    }
    if (threadIdx.x == 0) off[n] = carry;
}

// rec[pos] = {w = norm[src]*norm[dst] (hi 32), src (lo 32)}, bucketed by dst
__global__ void scatter_kernel(const int* __restrict__ src, const int* __restrict__ dst,
                               const float* __restrict__ nrm, const int* __restrict__ off,
                               int* __restrict__ cur, u64* __restrict__ rec, int E) {
    int e = blockIdx.x * blockDim.x + threadIdx.x;
    if (e >= E) return;
    int s = src[e], d = dst[e];
    float w = nrm[s] * nrm[d];
    int pos = off[d] + atomicAdd(&cur[d], 1);
    rec[pos] = ((u64)__float_as_uint(w) << 32) | (unsigned)s;
}

// ---------------- per-layer kernels ----------------

// C[N][64] = A[N][64] @ W[64][64]; block = 256 thr handles 64 rows; W + A tile in LDS.
__global__ void mm_kernel(const float* __restrict__ A, const float* __restrict__ W,
                          float* __restrict__ C, int N) {
    __shared__ float As[64][64];
    __shared__ float Ws[64][64];
    int tx = threadIdx.x;
    #pragma unroll
    for (int k = 0; k < 4; ++k)
        ((float4*)Ws)[tx + 256 * k] = ((const float4*)W)[tx + 256 * k];
    int rowBase = blockIdx.x * 64;
    #pragma unroll
    for (int k = 0; k < 4; ++k) {
        int f = tx + 256 * k;            // float4 index within tile (16 per row)
        int row = rowBase + (f >> 4);
        float4 v = make_float4(0.f, 0.f, 0.f, 0.f);
        if (row < N) v = ((const float4*)A)[(size_t)rowBase * 16 + f];
        ((float4*)As)[f] = v;
    }
    __syncthreads();
    int c = tx & 63;
    int r0 = tx >> 6;
    #pragma unroll
    for (int i = 0; i < 16; ++i) {
        int r = r0 * 16 + i;
        int row = rowBase + r;
        if (row < N) {
            float acc = 0.f;
            #pragma unroll
            for (int k = 0; k < 64; ++k) acc = fmaf(As[r][k], Ws[k][c], acc);
            C[(size_t)row * 64 + c] = acc;
        }
    }
}

// one wave per node, lane = feature; gathers are coalesced 256B rows; no atomics.
__global__ void agg_kernel(const float* __restrict__ tmp, const u64* __restrict__ rec,
                           const int* __restrict__ off, const float* __restrict__ nrm,
                           const float* __restrict__ bias, float* __restrict__ out, int N) {
    int node = blockIdx.x * (blockDim.x >> 6) + (threadIdx.x >> 6);
    int lane = threadIdx.x & 63;
    if (node >= N) return;
    int s = off[node], e = off[node + 1];
    float acc = 0.f;
    int i = s;
    for (; i + 4 <= e; i += 4) {
        u64 r0 = rec[i], r1 = rec[i + 1], r2 = rec[i + 2], r3 = rec[i + 3];
        int   s0 = (int)(unsigned)r0,  s1 = (int)(unsigned)r1;
        int   s2 = (int)(unsigned)r2,  s3 = (int)(unsigned)r3;
        float w0 = __uint_as_float((unsigned)(r0 >> 32));
        float w1 = __uint_as_float((unsigned)(r1 >> 32));
        float w2 = __uint_as_float((unsigned)(r2 >> 32));
        float w3 = __uint_as_float((unsigned)(r3 >> 32));
        float v0 = tmp[(size_t)s0 * 64 + lane];
        float v1 = tmp[(size_t)s1 * 64 + lane];
        float v2 = tmp[(size_t)s2 * 64 + lane];
        float v3 = tmp[(size_t)s3 * 64 + lane];
        acc = fmaf(w0, v0, acc);
        acc = fmaf(w1, v1, acc);
        acc = fmaf(w2, v2, acc);
        acc = fmaf(w3, v3, acc);
    }
    for (; i < e; ++i) {
        u64 r = rec[i];
        int   sn = (int)(unsigned)r;
        float w  = __uint_as_float((unsigned)(r >> 32));
        acc = fmaf(w, tmp[(size_t)sn * 64 + lane], acc);
    }
    float nn = nrm[node];
    float self = tmp[(size_t)node * 64 + lane];
    float res = acc + self * nn * nn + bias[lane];
    out[(size_t)node * 64 + lane] = fmaxf(res, 0.f);
}

// one wave per graph: mean over node range, dot with Wp, + bp
__global__ void readout_kernel(const float* __restrict__ h, const int* __restrict__ ptr,
                               const float* __restrict__ Wp, const float* __restrict__ bp,
                               float* __restrict__ out, int G) {
    int g = blockIdx.x * (blockDim.x >> 6) + (threadIdx.x >> 6);
    int lane = threadIdx.x & 63;
    if (g >= G) return;
    int s = ptr[g], e = ptr[g + 1];
    float acc = 0.f;
    for (int r = s; r < e; ++r) acc += h[(size_t)r * 64 + lane];
    float val = (acc / (float)(e - s)) * Wp[lane];
    #pragma unroll
    for (int o = 32; o > 0; o >>= 1) val += __shfl_down(val, o, 64);
    if (lane == 0) out[g] = val + bp[0];
}

// ---------------- launch ----------------

extern "C" void kernel_launch(void* const* d_in, const int* in_sizes, int n_in,
                              void* d_out, int out_size, void* d_ws, size_t ws_size,
                              hipStream_t stream) {
    const float* x  = (const float*)d_in[0];
    const int*   ei = (const int*)d_in[1];
    const int*   ptr = (const int*)d_in[2];
    const float* W1 = (const float*)d_in[3];
    const float* b1 = (const float*)d_in[4];
    const float* W2 = (const float*)d_in[5];
    const float* b2 = (const float*)d_in[6];
    const float* W3 = (const float*)d_in[7];
    const float* b3 = (const float*)d_in[8];
    const float* Wp = (const float*)d_in[9];
    const float* bp = (const float*)d_in[10];
    float* out = (float*)d_out;

    const int D = 64;
    int N = in_sizes[0] / D;
    int E = in_sizes[1] / 2;
    int G = in_sizes[2] - 1;

    // workspace layout (~36.6 MB)
    char* w = (char*)d_ws;
    u64*   rec  = (u64*)w;   w += (size_t)E * 8;
    float* bufA = (float*)w; w += (size_t)N * D * 4;
    float* bufB = (float*)w; w += (size_t)N * D * 4;
    int*   cnt  = (int*)w;   w += (size_t)N * 4;
    int*   offs = (int*)w;   w += (size_t)(N + 1) * 4;
    int*   cur  = (int*)w;   w += (size_t)N * 4;
    float* nrm  = (float*)w; w += (size_t)N * 4;

    hipMemsetAsync(cnt, 0, (size_t)N * 4, stream);
    hipMemsetAsync(cur, 0, (size_t)N * 4, stream);

    const int* src = ei;
    const int* dst = ei + E;

    count_kernel  <<<(E + 255) / 256, 256, 0, stream>>>(dst, cnt, E);
    norm_kernel   <<<(N + 255) / 256, 256, 0, stream>>>(cnt, nrm, N);
    scan_kernel   <<<1, 1024, 0, stream>>>(cnt, offs, N);
    scatter_kernel<<<(E + 255) / 256, 256, 0, stream>>>(src, dst, nrm, offs, cur, rec, E);

    const float* hin = x;
    const float* Wl[3] = {W1, W2, W3};
    const float* bl[3] = {b1, b2, b3};
    for (int l = 0; l < 3; ++l) {
        mm_kernel <<<(N + 63) / 64, 256, 0, stream>>>(hin, Wl[l], bufA, N);
        agg_kernel<<<(N + 3) / 4, 256, 0, stream>>>(bufA, rec, offs, nrm, bl[l], bufB, N);
        hin = bufB;
    }
    readout_kernel<<<(G + 3) / 4, 256, 0, stream>>>(bufB, ptr, Wp, bp, out, G);
}

// Round 3
// 478.267 us; speedup vs baseline: 1.1827x; 1.1827x over previous
//
#include <hip/hip_runtime.h>
#include <hip/hip_bf16.h>

typedef unsigned long long u64;

// ---------------- CSR build ----------------

__global__ void count_kernel(const int* __restrict__ dst, int* __restrict__ cnt, int E) {
    int e = blockIdx.x * blockDim.x + threadIdx.x;
    if (e < E) atomicAdd(&cnt[dst[e]], 1);
}

// wave-aggregated bucket allocation + norm. Bucket ORDER is arbitrary (only
// contiguity matters for agg), so no ordered prefix sum is needed: one
// atomicAdd per wave on a global cursor replaces the 91us serial scan.
__global__ void allocnorm_kernel(const int* __restrict__ cnt, int* __restrict__ base,
                                 float* __restrict__ nrm, int* __restrict__ total, int N) {
    int n = blockIdx.x * blockDim.x + threadIdx.x;
    int lane = threadIdx.x & 63;
    int c = (n < N) ? cnt[n] : 0;
    int pref = c;                       // inclusive wave prefix
    #pragma unroll
    for (int o = 1; o < 64; o <<= 1) {
        int t = __shfl_up(pref, o, 64);
        if (lane >= o) pref += t;
    }
    int wtot = __shfl(pref, 63, 64);
    int b0 = 0;
    if (lane == 63) b0 = atomicAdd(total, wtot);
    b0 = __shfl(b0, 63, 64);
    if (n < N) {
        base[n] = b0 + (pref - c);      // exclusive within wave
        nrm[n]  = rsqrtf((float)c + 1.0f);
    }
}

// rec[pos] = {w = norm[src]*norm[dst] (hi 32), src (lo 32)}, bucketed by dst
__global__ void scatter_kernel(const int* __restrict__ src, const int* __restrict__ dst,
                               const float* __restrict__ nrm, const int* __restrict__ base,
                               int* __restrict__ cur, u64* __restrict__ rec, int E) {
    int e = blockIdx.x * blockDim.x + threadIdx.x;
    if (e >= E) return;
    int s = src[e], d = dst[e];
    float w = nrm[s] * nrm[d];
    int pos = base[d] + atomicAdd(&cur[d], 1);
    rec[pos] = ((u64)__float_as_uint(w) << 32) | (unsigned)s;
}

// ---------------- per-layer kernels ----------------

// C[N][64] = A[N][64] @ W[64][64]; block = 256 thr handles 64 rows; W + A tile in LDS.
__global__ void mm_kernel(const float* __restrict__ A, const float* __restrict__ W,
                          float* __restrict__ C, int N) {
    __shared__ float As[64][64];
    __shared__ float Ws[64][64];
    int tx = threadIdx.x;
    #pragma unroll
    for (int k = 0; k < 4; ++k)
        ((float4*)Ws)[tx + 256 * k] = ((const float4*)W)[tx + 256 * k];
    int rowBase = blockIdx.x * 64;
    #pragma unroll
    for (int k = 0; k < 4; ++k) {
        int f = tx + 256 * k;            // float4 index within tile (16 per row)
        int row = rowBase + (f >> 4);
        float4 v = make_float4(0.f, 0.f, 0.f, 0.f);
        if (row < N) v = ((const float4*)A)[(size_t)rowBase * 16 + f];
        ((float4*)As)[f] = v;
    }
    __syncthreads();
    int c = tx & 63;
    int r0 = tx >> 6;
    #pragma unroll
    for (int i = 0; i < 16; ++i) {
        int r = r0 * 16 + i;
        int row = rowBase + r;
        if (row < N) {
            float acc = 0.f;
            #pragma unroll
            for (int k = 0; k < 64; ++k) acc = fmaf(As[r][k], Ws[k][c], acc);
            C[(size_t)row * 64 + c] = acc;
        }
    }
}

// one wave per node, lane = feature; gathers are coalesced 256B rows; no atomics.
__global__ void agg_kernel(const float* __restrict__ tmp, const u64* __restrict__ rec,
                           const int* __restrict__ base, const int* __restrict__ cnt,
                           const float* __restrict__ nrm, const float* __restrict__ bias,
                           float* __restrict__ out, int N) {
    int node = blockIdx.x * (blockDim.x >> 6) + (threadIdx.x >> 6);
    int lane = threadIdx.x & 63;
    if (node >= N) return;
    int s = base[node];
    int e = s + cnt[node];
    float acc = 0.f;
    int i = s;
    for (; i + 8 <= e; i += 8) {
        u64 r0 = rec[i],     r1 = rec[i + 1], r2 = rec[i + 2], r3 = rec[i + 3];
        u64 r4 = rec[i + 4], r5 = rec[i + 5], r6 = rec[i + 6], r7 = rec[i + 7];
        float v0 = tmp[(size_t)(unsigned)(r0 & 0xffffffffu) * 64 + lane];
        float v1 = tmp[(size_t)(unsigned)(r1 & 0xffffffffu) * 64 + lane];
        float v2 = tmp[(size_t)(unsigned)(r2 & 0xffffffffu) * 64 + lane];
        float v3 = tmp[(size_t)(unsigned)(r3 & 0xffffffffu) * 64 + lane];
        float v4 = tmp[(size_t)(unsigned)(r4 & 0xffffffffu) * 64 + lane];
        float v5 = tmp[(size_t)(unsigned)(r5 & 0xffffffffu) * 64 + lane];
        float v6 = tmp[(size_t)(unsigned)(r6 & 0xffffffffu) * 64 + lane];
        float v7 = tmp[(size_t)(unsigned)(r7 & 0xffffffffu) * 64 + lane];
        acc = fmaf(__uint_as_float((unsigned)(r0 >> 32)), v0, acc);
        acc = fmaf(__uint_as_float((unsigned)(r1 >> 32)), v1, acc);
        acc = fmaf(__uint_as_float((unsigned)(r2 >> 32)), v2, acc);
        acc = fmaf(__uint_as_float((unsigned)(r3 >> 32)), v3, acc);
        acc = fmaf(__uint_as_float((unsigned)(r4 >> 32)), v4, acc);
        acc = fmaf(__uint_as_float((unsigned)(r5 >> 32)), v5, acc);
        acc = fmaf(__uint_as_float((unsigned)(r6 >> 32)), v6, acc);
        acc = fmaf(__uint_as_float((unsigned)(r7 >> 32)), v7, acc);
    }
    for (; i < e; ++i) {
        u64 r = rec[i];
        acc = fmaf(__uint_as_float((unsigned)(r >> 32)),
                   tmp[(size_t)(unsigned)(r & 0xffffffffu) * 64 + lane], acc);
    }
    float nn = nrm[node];
    float self = tmp[(size_t)node * 64 + lane];
    float res = acc + self * nn * nn + bias[lane];
    out[(size_t)node * 64 + lane] = fmaxf(res, 0.f);
}

// one wave per graph: mean over node range, dot with Wp, + bp
__global__ void readout_kernel(const float* __restrict__ h, const int* __restrict__ ptr,
                               const float* __restrict__ Wp, const float* __restrict__ bp,
                               float* __restrict__ out, int G) {
    int g = blockIdx.x * (blockDim.x >> 6) + (threadIdx.x >> 6);
    int lane = threadIdx.x & 63;
    if (g >= G) return;
    int s = ptr[g], e = ptr[g + 1];
    float acc = 0.f;
    for (int r = s; r < e; ++r) acc += h[(size_t)r * 64 + lane];
    float val = (acc / (float)(e - s)) * Wp[lane];
    #pragma unroll
    for (int o = 32; o > 0; o >>= 1) val += __shfl_down(val, o, 64);
    if (lane == 0) out[g] = val + bp[0];
}

// ---------------- launch ----------------

extern "C" void kernel_launch(void* const* d_in, const int* in_sizes, int n_in,
                              void* d_out, int out_size, void* d_ws, size_t ws_size,
                              hipStream_t stream) {
    const float* x  = (const float*)d_in[0];
    const int*   ei = (const int*)d_in[1];
    const int*   ptr = (const int*)d_in[2];
    const float* W1 = (const float*)d_in[3];
    const float* b1 = (const float*)d_in[4];
    const float* W2 = (const float*)d_in[5];
    const float* b2 = (const float*)d_in[6];
    const float* W3 = (const float*)d_in[7];
    const float* b3 = (const float*)d_in[8];
    const float* Wp = (const float*)d_in[9];
    const float* bp = (const float*)d_in[10];
    float* out = (float*)d_out;

    const int D = 64;
    int N = in_sizes[0] / D;
    int E = in_sizes[1] / 2;
    int G = in_sizes[2] - 1;

    // workspace layout (~36.4 MB); cnt|cur|total contiguous -> one memset
    char* w = (char*)d_ws;
    u64*   rec  = (u64*)w;   w += (size_t)E * 8;
    float* bufA = (float*)w; w += (size_t)N * D * 4;
    float* bufB = (float*)w; w += (size_t)N * D * 4;
    int*   cnt  = (int*)w;   w += (size_t)N * 4;
    int*   cur  = (int*)w;   w += (size_t)N * 4;
    int*   total= (int*)w;   w += 4;
    int*   base = (int*)w;   w += (size_t)N * 4;
    float* nrm  = (float*)w; w += (size_t)N * 4;

    hipMemsetAsync(cnt, 0, (size_t)(2 * N + 1) * 4, stream);

    const int* src = ei;
    const int* dst = ei + E;

    count_kernel    <<<(E + 255) / 256, 256, 0, stream>>>(dst, cnt, E);
    allocnorm_kernel<<<(N + 255) / 256, 256, 0, stream>>>(cnt, base, nrm, total, N);
    scatter_kernel  <<<(E + 255) / 256, 256, 0, stream>>>(src, dst, nrm, base, cur, rec, E);

    const float* hin = x;
    const float* Wl[3] = {W1, W2, W3};
    const float* bl[3] = {b1, b2, b3};
    for (int l = 0; l < 3; ++l) {
        mm_kernel <<<(N + 63) / 64, 256, 0, stream>>>(hin, Wl[l], bufA, N);
        agg_kernel<<<(N + 3) / 4, 256, 0, stream>>>(bufA, rec, base, cnt, nrm, bl[l], bufB, N);
        hin = bufB;
    }
    readout_kernel<<<(G + 3) / 4, 256, 0, stream>>>(bufB, ptr, Wp, bp, out, G);
}